// Round 7
// baseline (635.606 us; speedup 1.0000x reference)
//
#include <hip/hip_runtime.h>

// Round 7: two-level (src-window x dst-bucket) partition; LDS-local aggregation,
// no global scatter/atomic combine. Assumes Nn <= 131072 (17-bit ids).

#define WSH   14        // src window = 16384 nodes (1 MB of hs)
#define MAXW  8
#define DSH   6         // dst bucket = 64 nodes
#define MAXB  2048      // max dst buckets (Nn<=131072)
#define WCH   4096      // edges/chunk in wpart
#define DCH   4096      // edges/chunk in dpart
#define ACH   2048      // staged edges/chunk in agg

// ---------- bf16 helpers ----------
__device__ __forceinline__ float bf2f(unsigned int u16) {
    return __uint_as_float(u16 << 16);
}
__device__ __forceinline__ unsigned short f2bf(float f) {
    unsigned int u = __float_as_uint(f);
    u += 0x7fffu + ((u >> 16) & 1u);
    return (unsigned short)(u >> 16);
}

// ---------------- kernel: runtime encoding detection ----------------
__global__ __launch_bounds__(256) void k_detect(const unsigned int* __restrict__ xw,
                                                const unsigned int* __restrict__ eiw,
                                                int* __restrict__ flags) {
    __shared__ int votes[2];
    int tid = threadIdx.x;
    if (tid == 0) { votes[0] = 0; votes[1] = 0; }
    __syncthreads();
    unsigned int w = xw[tid];
    unsigned int lo = w & 0xffffu;
    unsigned int elo = (lo >> 7) & 0xffu;
    int bfvote = (lo == 0u || (elo >= 100u && elo <= 140u)) ? 1 : 0;
    int nzvote = (eiw[2 * tid + 1] != 0u) ? 1 : 0;
    atomicAdd(&votes[0], bfvote);
    atomicAdd(&votes[1], nzvote);
    __syncthreads();
    if (tid == 0) {
        flags[0] = (votes[0] >= 160) ? 1 : 0;
        flags[1] = (votes[1] == 0) ? 1 : 0;
    }
}

// ---------------- kernel: per-src-window histogram ----------------
__global__ __launch_bounds__(256) void k_whist(const int* __restrict__ ei,
                                               const int* __restrict__ flags,
                                               int* __restrict__ whist, int E, int Nn, int NW) {
    __shared__ int lh[MAXW];
    int tid = threadIdx.x;
    if (tid < MAXW) lh[tid] = 0;
    __syncthreads();
    int is64 = flags[1];
    int e0 = blockIdx.x * 8192;
    for (int i = 0; i < 32; ++i) {
        int e = e0 + i * 256 + tid;
        if (e < E) {
            int s, d;
            if (is64) { s = ei[2 * e]; d = ei[2 * (E + e)]; }
            else      { s = ei[e];     d = ei[E + e]; }
            if ((unsigned)s < (unsigned)Nn && (unsigned)d < (unsigned)Nn)
                atomicAdd(&lh[s >> WSH], 1);
        }
    }
    __syncthreads();
    if (tid < NW && lh[tid]) atomicAdd(&whist[tid], lh[tid]);
}

// ---------------- kernel: scan windows -> wbase, wcursor ----------------
__global__ __launch_bounds__(64) void k_wscan(const int* __restrict__ whist,
                                              int* __restrict__ wbase,
                                              int* __restrict__ wcursor, int NW) {
    if (threadIdx.x == 0) {
        int run = 0;
        for (int w = 0; w < NW; ++w) {
            wbase[w] = run; wcursor[w] = run; run += whist[w];
        }
        wbase[NW] = run;
    }
}

// ---------------- kernel: partition edges by src-window ----------------
// wbkt entry: s_low (WSH bits) | d << WSH
__global__ __launch_bounds__(256) void k_wpart(const int* __restrict__ ei,
                                               const int* __restrict__ flags,
                                               int* __restrict__ wcursor,
                                               unsigned int* __restrict__ wbkt,
                                               int E, int Nn, int NW) {
    __shared__ unsigned int stage[WCH];
    __shared__ int lh[MAXW], lex[MAXW + 1], lbase[MAXW];
    int tid = threadIdx.x;
    if (tid < MAXW) lh[tid] = 0;
    __syncthreads();
    int is64 = flags[1];
    int e0 = blockIdx.x * WCH;
    int ss[16], dd[16];
    #pragma unroll
    for (int i = 0; i < 16; ++i) {
        int e = e0 + i * 256 + tid;
        int s = -1, d = -1;
        if (e < E) {
            if (is64) { s = ei[2 * e]; d = ei[2 * (E + e)]; }
            else      { s = ei[e];     d = ei[E + e]; }
            if ((unsigned)s >= (unsigned)Nn || (unsigned)d >= (unsigned)Nn) { s = -1; d = -1; }
        }
        ss[i] = s; dd[i] = d;
        if (s >= 0) atomicAdd(&lh[s >> WSH], 1);
    }
    __syncthreads();
    if (tid == 0) {
        int run = 0;
        for (int w = 0; w < NW; ++w) { lex[w] = run; run += lh[w]; }
        lex[NW] = run;
    }
    __syncthreads();
    if (tid < NW) {
        int c = lh[tid];
        lbase[tid] = c ? atomicAdd(&wcursor[tid], c) : 0;
        lh[tid] = lex[tid];   // becomes running cursor
    }
    __syncthreads();
    #pragma unroll
    for (int i = 0; i < 16; ++i) {
        if (ss[i] >= 0) {
            int b = ss[i] >> WSH;
            int q = atomicAdd(&lh[b], 1);
            stage[q] = (unsigned)(ss[i] & ((1 << WSH) - 1)) | ((unsigned)dd[i] << WSH);
        }
    }
    __syncthreads();
    int tot = lex[NW];
    for (int q = tid; q < tot; q += 256) {
        int lo = 0, hi = NW - 1;
        while (lo < hi) { int mid = (lo + hi + 1) >> 1; if (lex[mid] <= q) lo = mid; else hi = mid - 1; }
        wbkt[lbase[lo] + q - lex[lo]] = stage[q];
    }
}

// ---------------- kernel: histogram of (window, dst-bucket) ----------------
__global__ __launch_bounds__(256) void k_hist2(const unsigned int* __restrict__ wbkt,
                                               const int* __restrict__ wbase,
                                               int* __restrict__ ghist,
                                               int E, int NW, int NBD, int NP) {
    extern __shared__ int lh2[];   // NP ints
    __shared__ int lwb[MAXW + 1];
    int tid = threadIdx.x;
    for (int i = tid; i < NP; i += 256) lh2[i] = 0;
    if (tid <= NW) lwb[tid] = wbase[tid];
    __syncthreads();
    int wtot = lwb[NW];
    int i0 = blockIdx.x * 16384;
    for (int r = 0; r < 64; ++r) {
        int idx = i0 + r * 256 + tid;
        if (idx < wtot) {
            unsigned u = wbkt[idx];
            int d = (int)(u >> WSH);
            int lo = 0, hi = NW - 1;
            while (lo < hi) { int mid = (lo + hi + 1) >> 1; if (lwb[mid] <= idx) lo = mid; else hi = mid - 1; }
            atomicAdd(&lh2[lo * NBD + (d >> DSH)], 1);
        }
    }
    __syncthreads();
    for (int i = tid; i < NP; i += 256) {
        int c = lh2[i];
        if (c) atomicAdd(&ghist[i], c);
    }
}

// ---------------- kernel: scan NP bins -> gbase, gcur ----------------
__global__ __launch_bounds__(1024) void k_scanB(const int* __restrict__ ghist,
                                                int* __restrict__ gbase,
                                                int* __restrict__ gcur, int NP) {
    __shared__ int sa[1024], sb2[1024];
    int tid = threadIdx.x;
    int run = 0;
    for (int b0 = 0; b0 < NP; b0 += 1024) {
        int idx = b0 + tid;
        int v = (idx < NP) ? ghist[idx] : 0;
        sa[tid] = v;
        __syncthreads();
        int* cur = sa; int* nxt = sb2;
        for (int off = 1; off < 1024; off <<= 1) {
            nxt[tid] = cur[tid] + ((tid >= off) ? cur[tid - off] : 0);
            __syncthreads();
            int* t = cur; cur = nxt; nxt = t;
        }
        int incl = cur[tid];
        int excl = run + incl - v;
        if (idx < NP) { gbase[idx] = excl; gcur[idx] = excl; }
        int tot = cur[1023];
        __syncthreads();
        run += tot;
    }
    if (tid == 0) gbase[NP] = run;
}

// ---------------- kernel: partition window edges by dst-bucket ----------------
// bkt entry: s_full (17 bits) | (d&63) << 17
__global__ __launch_bounds__(256) void k_dpart(const unsigned int* __restrict__ wbkt,
                                               const int* __restrict__ wbase,
                                               int* __restrict__ gcur,
                                               unsigned int* __restrict__ bkt,
                                               int NCH, int NW, int NBD) {
    __shared__ int A[MAXB];      // hist -> cursor
    __shared__ int Ex[MAXB];     // exclusive offsets
    __shared__ int Boff[MAXB];   // global base - excl
    __shared__ unsigned int stg[DCH];
    __shared__ int sc[2][256];
    __shared__ int stot_s;
    int w = blockIdx.x / NCH;
    int c = blockIdx.x % NCH;
    int w0 = wbase[w], w1 = wbase[w + 1];
    int st = w0 + c * DCH;
    if (st >= w1) return;                 // uniform per block
    int en = min(st + DCH, w1);
    int tid = threadIdx.x;
    for (int i = tid; i < NBD; i += 256) A[i] = 0;
    __syncthreads();
    unsigned int us[16]; int vld[16];
    #pragma unroll
    for (int i = 0; i < 16; ++i) {
        int idx = st + i * 256 + tid;
        vld[i] = (idx < en);
        us[i] = vld[i] ? wbkt[idx] : 0u;
        if (vld[i]) atomicAdd(&A[(us[i] >> WSH) >> DSH], 1);
    }
    __syncthreads();
    // serial-per-thread (8 bins) + block scan
    int myb0 = tid * 8;
    int cnts[8], loc[8];
    int run = 0;
    #pragma unroll
    for (int k = 0; k < 8; ++k) {
        int b = myb0 + k;
        int v = (b < NBD) ? A[b] : 0;
        cnts[k] = v; loc[k] = run; run += v;
    }
    sc[0][tid] = run;
    __syncthreads();
    int pi = 0;
    for (int off = 1; off < 256; off <<= 1) {
        sc[pi ^ 1][tid] = sc[pi][tid] + ((tid >= off) ? sc[pi][tid - off] : 0);
        __syncthreads();
        pi ^= 1;
    }
    int texcl = sc[pi][tid] - run;
    if (tid == 255) stot_s = sc[pi][255];
    __syncthreads();
    #pragma unroll
    for (int k = 0; k < 8; ++k) {
        int b = myb0 + k;
        if (b < NBD) {
            int ex = texcl + loc[k];
            Ex[b] = ex; A[b] = ex;
            Boff[b] = cnts[k] ? (atomicAdd(&gcur[w * NBD + b], cnts[k]) - ex) : 0;
        }
    }
    __syncthreads();
    #pragma unroll
    for (int i = 0; i < 16; ++i) {
        if (vld[i]) {
            unsigned u = us[i];
            int d = (int)(u >> WSH);
            int b = d >> DSH;
            int q = atomicAdd(&A[b], 1);
            unsigned s_full = (unsigned)(w << WSH) + (u & ((1u << WSH) - 1u));
            stg[q] = s_full | ((unsigned)(d & 63) << 17);
        }
    }
    __syncthreads();
    int stot = stot_s;
    for (int q = tid; q < stot; q += 256) {
        int lo = 0, hi = NBD - 1;
        while (lo < hi) { int mid = (lo + hi + 1) >> 1; if (Ex[mid] <= q) lo = mid; else hi = mid - 1; }
        bkt[Boff[lo] + q] = stg[q];
    }
}

// ---------------- kernel: per-dst-bucket degree -> dinv ----------------
__global__ __launch_bounds__(256) void k_dinvB(const unsigned int* __restrict__ bkt,
                                               const int* __restrict__ gbase,
                                               float* __restrict__ dinv,
                                               int NW, int NBD, int Nn) {
    __shared__ int cnt[64];
    int tid = threadIdx.x, b = blockIdx.x;
    if (tid < 64) cnt[tid] = 0;
    __syncthreads();
    for (int w = 0; w < NW; ++w) {
        int bin = w * NBD + b;
        int st = gbase[bin], en = gbase[bin + 1];
        for (int e = st + tid; e < en; e += 256)
            atomicAdd(&cnt[(bkt[e] >> 17) & 63], 1);
    }
    __syncthreads();
    if (tid < 64) {
        int n = b * 64 + tid;
        if (n < Nn) dinv[n] = rsqrtf((float)(cnt[tid] + 1));  // +1 self loop
    }
}

// ---------------- kernel: hs = (x @ W1) * dinv ----------------
__global__ __launch_bounds__(256) void k_gemm1(const void* __restrict__ xraw,
                                               const void* __restrict__ w1raw,
                                               const int* __restrict__ flags,
                                               const float* __restrict__ dinv,
                                               float* __restrict__ hs, int Nn) {
    __shared__ float sWt[16 * 132];
    const int isbf = flags[0];
    const ushort* xb = (const ushort*)xraw;
    const float* xf = (const float*)xraw;
    int tid = threadIdx.x;
    if (isbf) {
        const ushort* w1 = (const ushort*)w1raw;
        for (int i = tid; i < 2048; i += 256) {
            int k = i >> 4, j = i & 15;
            sWt[j * 132 + k] = bf2f(w1[i]);
        }
    } else {
        const float* w1 = (const float*)w1raw;
        for (int i = tid; i < 2048; i += 256) {
            int k = i >> 4, j = i & 15;
            sWt[j * 132 + k] = w1[i];
        }
    }
    __syncthreads();
    int hq = tid & 3;
    int nodeq = tid >> 2;
    int n0 = blockIdx.x * 256 + nodeq * 4;
    float acc[4][4] = {};
    for (int ko = 0; ko < 16; ++ko) {
        float xv[4][8];
        #pragma unroll
        for (int r = 0; r < 4; ++r) {
            int n = n0 + r;
            if (n < Nn) {
                if (isbf) {
                    uint4 q = *reinterpret_cast<const uint4*>(xb + (size_t)n * 128 + ko * 8);
                    xv[r][0] = bf2f(q.x & 0xffffu); xv[r][1] = bf2f(q.x >> 16);
                    xv[r][2] = bf2f(q.y & 0xffffu); xv[r][3] = bf2f(q.y >> 16);
                    xv[r][4] = bf2f(q.z & 0xffffu); xv[r][5] = bf2f(q.z >> 16);
                    xv[r][6] = bf2f(q.w & 0xffffu); xv[r][7] = bf2f(q.w >> 16);
                } else {
                    const float4* p = reinterpret_cast<const float4*>(xf + (size_t)n * 128 + ko * 8);
                    float4 a = p[0], bb = p[1];
                    xv[r][0] = a.x; xv[r][1] = a.y; xv[r][2] = a.z; xv[r][3] = a.w;
                    xv[r][4] = bb.x; xv[r][5] = bb.y; xv[r][6] = bb.z; xv[r][7] = bb.w;
                }
            } else {
                #pragma unroll
                for (int u = 0; u < 8; ++u) xv[r][u] = 0.f;
            }
        }
        #pragma unroll
        for (int cc = 0; cc < 4; ++cc) {
            const float* wr = &sWt[(hq * 4 + cc) * 132 + ko * 8];
            float4 w0 = *reinterpret_cast<const float4*>(wr);
            float4 w1v = *reinterpret_cast<const float4*>(wr + 4);
            #pragma unroll
            for (int r = 0; r < 4; ++r) {
                acc[r][cc] += xv[r][0] * w0.x + xv[r][1] * w0.y + xv[r][2] * w0.z + xv[r][3] * w0.w
                            + xv[r][4] * w1v.x + xv[r][5] * w1v.y + xv[r][6] * w1v.z + xv[r][7] * w1v.w;
            }
        }
    }
    #pragma unroll
    for (int r = 0; r < 4; ++r) {
        int n = n0 + r;
        if (n < Nn) {
            float dv = dinv[n];
            float4 o = make_float4(acc[r][0] * dv, acc[r][1] * dv, acc[r][2] * dv, acc[r][3] * dv);
            *reinterpret_cast<float4*>(hs + (size_t)n * 16 + hq * 4) = o;
        }
    }
}

// ---------------- kernel: per-bucket aggregate (windowed) + fused epilogue ----------------
__global__ __launch_bounds__(256) void k_agg(const unsigned int* __restrict__ bkt,
                                             const int* __restrict__ gbase,
                                             const float* __restrict__ hs,
                                             const float* __restrict__ dinv,
                                             const void* __restrict__ b1raw,
                                             const void* __restrict__ wpraw,
                                             const void* __restrict__ bpraw,
                                             const int* __restrict__ flags,
                                             void* __restrict__ outraw,
                                             int NW, int NBD, int Nn) {
    __shared__ float sAgg[64 * 16];        // 4 KB
    __shared__ float sWp[256];
    __shared__ float sdv[64];
    __shared__ unsigned int sStage[ACH];   // 8 KB
    int tid = threadIdx.x, b = blockIdx.x;
    const int isbf = flags[0];
    int n0 = b * 64;
    sWp[tid] = isbf ? bf2f(((const ushort*)wpraw)[tid]) : ((const float*)wpraw)[tid];
    {   // init sAgg with self-loop term hs[own nodes]
        int node = n0 + (tid >> 2);
        if (node < Nn) {
            float4 v = *reinterpret_cast<const float4*>(hs + (size_t)node * 16 + (tid & 3) * 4);
            *reinterpret_cast<float4*>(&sAgg[tid * 4]) = v;
        } else {
            *reinterpret_cast<float4*>(&sAgg[tid * 4]) = make_float4(0.f, 0.f, 0.f, 0.f);
        }
    }
    if (tid < 64) sdv[tid] = (n0 + tid < Nn) ? dinv[n0 + tid] : 0.f;
    __syncthreads();
    int g = tid >> 4, j = tid & 15;
    for (int w = 0; w < NW; ++w) {
        int bin = w * NBD + b;
        int st = gbase[bin], en = gbase[bin + 1];
        for (int c0 = st; c0 < en; c0 += ACH) {
            int C = min(ACH, en - c0);
            for (int q = tid; q < C; q += 256) sStage[q] = bkt[c0 + q];
            __syncthreads();
            for (int k0 = g * 8; k0 < C; k0 += 128) {
                unsigned pp[8]; float vv[8];
                #pragma unroll
                for (int i = 0; i < 8; ++i)
                    pp[i] = (k0 + i < C) ? sStage[k0 + i] : 0xffffffffu;
                #pragma unroll
                for (int i = 0; i < 8; ++i)
                    vv[i] = (pp[i] != 0xffffffffu) ? hs[(size_t)(pp[i] & 0x1ffffu) * 16 + j] : 0.f;
                #pragma unroll
                for (int i = 0; i < 8; ++i)
                    if (pp[i] != 0xffffffffu)
                        atomicAdd(&sAgg[((pp[i] >> 17) & 63u) * 16 + j], vv[i]);
            }
            __syncthreads();
        }
    }
    // fused epilogue: *dinv[d] + b1, relu, pool (@Wp+bp), softmax, store
    float b1v = isbf ? bf2f(((const ushort*)b1raw)[j]) : ((const float*)b1raw)[j];
    float bpv = isbf ? bf2f(((const ushort*)bpraw)[j]) : ((const float*)bpraw)[j];
    for (int p = 0; p < 4; ++p) {
        int i = p * 16 + g;
        float r = fmaxf(sAgg[i * 16 + j] * sdv[i] + b1v, 0.f);
        float lg = bpv;
        #pragma unroll
        for (int kk = 0; kk < 16; ++kk) lg += __shfl(r, kk, 16) * sWp[kk * 16 + j];
        float m = lg;
        #pragma unroll
        for (int off = 1; off < 16; off <<= 1) m = fmaxf(m, __shfl_xor(m, off, 16));
        float ev = __expf(lg - m);
        float ssum = ev;
        #pragma unroll
        for (int off = 1; off < 16; off <<= 1) ssum += __shfl_xor(ssum, off, 16);
        int n = n0 + i;
        if (n < Nn) {
            float v = ev / ssum;
            if (isbf) ((ushort*)outraw)[(size_t)n * 16 + j] = f2bf(v);
            else      ((float*)outraw)[(size_t)n * 16 + j] = v;
        }
    }
}

extern "C" void kernel_launch(void* const* d_in, const int* in_sizes, int n_in,
                              void* d_out, int out_size, void* d_ws, size_t ws_size,
                              hipStream_t stream) {
    const void* x  = d_in[0];
    const void* W1 = d_in[1];
    const void* b1 = d_in[2];
    const void* Wp = d_in[3];
    const void* bp = d_in[4];
    const int*  ei = (const int*)d_in[5];

    int Nn = in_sizes[0] / 128;
    int E  = in_sizes[5] / 2;
    int NW  = (Nn + (1 << WSH) - 1) >> WSH;
    int NBD = (Nn + 63) >> 6;
    int NP  = NW * NBD;
    int NCH = (E + DCH - 1) / DCH;

    size_t Ns = (size_t)Nn;
    char* ws = (char*)d_ws;
    size_t off = 0;
    auto alloc = [&](size_t bytes) { void* p = ws + off; off += (bytes + 63) & ~(size_t)63; return p; };
    int*          flags   = (int*)alloc(64);
    float*        hs      = (float*)alloc(Ns * 16 * 4);
    float*        dinv    = (float*)alloc(Ns * 4);
    int*          whist   = (int*)alloc(MAXW * 4);
    int*          wbase   = (int*)alloc((MAXW + 1) * 4);
    int*          wcursor = (int*)alloc(MAXW * 4);
    int*          ghist   = (int*)alloc((size_t)NP * 4);
    int*          gbase   = (int*)alloc((size_t)(NP + 1) * 4);
    int*          gcur    = (int*)alloc((size_t)NP * 4);
    unsigned int* wbkt    = (unsigned int*)alloc((size_t)E * 4);
    unsigned int* bkt     = (unsigned int*)alloc((size_t)E * 4);

    hipMemsetAsync(whist, 0, MAXW * 4, stream);
    hipMemsetAsync(ghist, 0, (size_t)NP * 4, stream);
    k_detect<<<1, 256, 0, stream>>>((const unsigned int*)x, (const unsigned int*)ei, flags);
    k_whist<<<(E + 8191) / 8192, 256, 0, stream>>>(ei, flags, whist, E, Nn, NW);
    k_wscan<<<1, 64, 0, stream>>>(whist, wbase, wcursor, NW);
    k_wpart<<<(E + WCH - 1) / WCH, 256, 0, stream>>>(ei, flags, wcursor, wbkt, E, Nn, NW);
    k_hist2<<<(E + 16383) / 16384, 256, (size_t)NP * 4, stream>>>(wbkt, wbase, ghist, E, NW, NBD, NP);
    k_scanB<<<1, 1024, 0, stream>>>(ghist, gbase, gcur, NP);
    k_dpart<<<NW * NCH, 256, 0, stream>>>(wbkt, wbase, gcur, bkt, NCH, NW, NBD);
    k_dinvB<<<NBD, 256, 0, stream>>>(bkt, gbase, dinv, NW, NBD, Nn);
    k_gemm1<<<(Nn + 255) / 256, 256, 0, stream>>>(x, W1, flags, dinv, hs, Nn);
    k_agg<<<NBD, 256, 0, stream>>>(bkt, gbase, hs, dinv, b1, Wp, bp, flags, d_out, NW, NBD, Nn);
}

// Round 8
// 288.748 us; speedup vs baseline: 2.2012x; 2.2012x over previous
//
#include <hip/hip_runtime.h>

// Round 8: one-level dst-bucket partition (256 nodes/bucket); k_aggS does
// per-chunk LDS counting-sort by node + register-run accumulation -> ZERO f32
// atomics in the hot loop. Assumes Nn <= 131072 (17-bit node ids).

// ---------- bf16 helpers ----------
__device__ __forceinline__ float bf2f(unsigned int u16) {
    return __uint_as_float(u16 << 16);
}
__device__ __forceinline__ unsigned short f2bf(float f) {
    unsigned int u = __float_as_uint(f);
    u += 0x7fffu + ((u >> 16) & 1u);
    return (unsigned short)(u >> 16);
}

__device__ __forceinline__ void atomAddF(float* p, float v) {
    unsafeAtomicAdd(p, v);  // global_atomic_add_f32
}

// ---------------- kernel: runtime encoding detection ----------------
__global__ __launch_bounds__(256) void k_detect(const unsigned int* __restrict__ xw,
                                                const unsigned int* __restrict__ eiw,
                                                int* __restrict__ flags) {
    __shared__ int votes[2];
    int tid = threadIdx.x;
    if (tid == 0) { votes[0] = 0; votes[1] = 0; }
    __syncthreads();
    unsigned int w = xw[tid];
    unsigned int lo = w & 0xffffu;
    unsigned int elo = (lo >> 7) & 0xffu;
    int bfvote = (lo == 0u || (elo >= 100u && elo <= 140u)) ? 1 : 0;
    int nzvote = (eiw[2 * tid + 1] != 0u) ? 1 : 0;
    atomicAdd(&votes[0], bfvote);
    atomicAdd(&votes[1], nzvote);
    __syncthreads();
    if (tid == 0) {
        flags[0] = (votes[0] >= 160) ? 1 : 0;
        flags[1] = (votes[1] == 0) ? 1 : 0;
    }
}

// ---------------- kernel: bucket histogram (bucket = dst>>8) ----------------
__global__ __launch_bounds__(256) void k_hist(const int* __restrict__ ei,
                                              const int* __restrict__ flags,
                                              int* __restrict__ hist, int E, int Nn) {
    __shared__ int lh[512];
    int tid = threadIdx.x;
    lh[tid] = 0; lh[tid + 256] = 0;
    __syncthreads();
    int is64 = flags[1];
    int e0 = blockIdx.x * 8192;
    for (int i = 0; i < 32; ++i) {
        int e = e0 + i * 256 + tid;
        if (e < E) {
            int d = is64 ? ei[2 * (E + e)] : ei[E + e];
            if ((unsigned)d < (unsigned)Nn) atomicAdd(&lh[d >> 8], 1);
        }
    }
    __syncthreads();
    int NB = (Nn + 255) >> 8;
    for (int b = tid; b < NB; b += 256) {
        int c = lh[b];
        if (c) atomicAdd(&hist[b], c);
    }
}

// ---------------- kernel: scan hist -> base[0..NB], cursor ----------------
__global__ __launch_bounds__(512) void k_scanB(const int* __restrict__ hist,
                                               int* __restrict__ base,
                                               int* __restrict__ cursor, int NB) {
    __shared__ int sa[512], sb[512];
    int tid = threadIdx.x;
    int v = (tid < NB) ? hist[tid] : 0;
    sa[tid] = v;
    __syncthreads();
    int* cur = sa; int* nxt = sb;
    for (int off = 1; off < 512; off <<= 1) {
        nxt[tid] = cur[tid] + ((tid >= off) ? cur[tid - off] : 0);
        __syncthreads();
        int* t = cur; cur = nxt; nxt = t;
    }
    int excl = cur[tid] - v;
    if (tid < NB) { base[tid] = excl; cursor[tid] = excl; }
    if (tid == NB - 1) base[NB] = excl + v;
}

// ---------------- kernel: partition edges into dst-buckets ----------------
// packed entry: s (17 bits) | (d&255) << 17
#define PCHUNK 4096
__global__ __launch_bounds__(256) void k_part(const int* __restrict__ ei,
                                              const int* __restrict__ flags,
                                              int* __restrict__ cursor,
                                              unsigned int* __restrict__ bkt,
                                              int E, int Nn) {
    __shared__ int lhist[512];
    __shared__ int lexcl[512];
    __shared__ int lbase[512];
    __shared__ int sa[512], sb[512];
    __shared__ unsigned int stage[PCHUNK];   // packed entries (16 KB)
    __shared__ int stot_s;
    int tid = threadIdx.x;
    lhist[tid] = 0; lhist[tid + 256] = 0;
    __syncthreads();
    int is64 = flags[1];
    int e0 = blockIdx.x * PCHUNK;
    int ss[16], dd[16];
    #pragma unroll
    for (int i = 0; i < 16; ++i) {
        int e = e0 + i * 256 + tid;
        int s = -1, d = -1;
        if (e < E) {
            if (is64) { s = ei[2 * e]; d = ei[2 * (E + e)]; }
            else      { s = ei[e];     d = ei[E + e]; }
            if ((unsigned)s >= (unsigned)Nn || (unsigned)d >= (unsigned)Nn) { s = -1; d = -1; }
        }
        ss[i] = s; dd[i] = d;
        if (d >= 0) atomicAdd(&lhist[d >> 8], 1);
    }
    __syncthreads();
    sa[tid] = lhist[tid]; sa[tid + 256] = lhist[tid + 256];
    __syncthreads();
    int* cur = sa; int* nxt = sb;
    for (int off = 1; off < 512; off <<= 1) {
        nxt[tid] = cur[tid] + ((tid >= off) ? cur[tid - off] : 0);
        int t2 = tid + 256;
        nxt[t2] = cur[t2] + ((t2 >= off) ? cur[t2 - off] : 0);
        __syncthreads();
        int* t = cur; cur = nxt; nxt = t;
    }
    lexcl[tid] = cur[tid] - lhist[tid];
    lexcl[tid + 256] = cur[tid + 256] - lhist[tid + 256];
    if (tid == 0) stot_s = cur[511];
    __syncthreads();
    for (int b = tid; b < 512; b += 256) {
        int c = lhist[b];
        lbase[b] = c ? atomicAdd(&cursor[b], c) : 0;
        lhist[b] = lexcl[b];
    }
    __syncthreads();
    #pragma unroll
    for (int i = 0; i < 16; ++i) {
        if (dd[i] >= 0) {
            int b = dd[i] >> 8;
            int q = atomicAdd(&lhist[b], 1);
            stage[q] = (unsigned)ss[i] | ((unsigned)(dd[i] & 255) << 17);
        }
    }
    __syncthreads();
    int stot = stot_s;
    for (int q = tid; q < stot; q += 256) {
        unsigned p = stage[q];
        // binary search bucket by position
        int lo = 0, hi = 511;
        while (lo < hi) { int mid = (lo + hi + 1) >> 1; if (lexcl[mid] <= q) lo = mid; else hi = mid - 1; }
        bkt[lbase[lo] + (q - lexcl[lo])] = p;
    }
}

// ---------------- kernel: per-bucket degree -> dinv ----------------
__global__ __launch_bounds__(256) void k_dinv(const unsigned int* __restrict__ bkt,
                                              const int* __restrict__ base,
                                              float* __restrict__ dinv, int Nn) {
    __shared__ int ldeg[256];
    int tid = threadIdx.x, b = blockIdx.x;
    ldeg[tid] = 0;
    __syncthreads();
    int st = base[b], en = base[b + 1];
    for (int e = st + tid; e < en; e += 256) {
        unsigned p = bkt[e];
        atomicAdd(&ldeg[(p >> 17) & 255], 1);
    }
    __syncthreads();
    int n = b * 256 + tid;
    if (n < Nn) dinv[n] = rsqrtf((float)(ldeg[tid] + 1));  // +1 self loop
}

// ---------------- kernel: hs = (x @ W1) * dinv ; agg init = hs (self loop) ----------------
__global__ __launch_bounds__(256) void k_gemm1(const void* __restrict__ xraw,
                                               const void* __restrict__ w1raw,
                                               const int* __restrict__ flags,
                                               const float* __restrict__ dinv,
                                               float* __restrict__ hs,
                                               float* __restrict__ agg, int Nn) {
    __shared__ float sWt[16 * 132];
    const int isbf = flags[0];
    const ushort* xb = (const ushort*)xraw;
    const float* xf = (const float*)xraw;
    int tid = threadIdx.x;
    if (isbf) {
        const ushort* w1 = (const ushort*)w1raw;
        for (int i = tid; i < 2048; i += 256) {
            int k = i >> 4, j = i & 15;
            sWt[j * 132 + k] = bf2f(w1[i]);
        }
    } else {
        const float* w1 = (const float*)w1raw;
        for (int i = tid; i < 2048; i += 256) {
            int k = i >> 4, j = i & 15;
            sWt[j * 132 + k] = w1[i];
        }
    }
    __syncthreads();
    int hq = tid & 3;
    int nodeq = tid >> 2;
    int n0 = blockIdx.x * 256 + nodeq * 4;
    float acc[4][4] = {};
    for (int ko = 0; ko < 16; ++ko) {
        float xv[4][8];
        #pragma unroll
        for (int r = 0; r < 4; ++r) {
            int n = n0 + r;
            if (n < Nn) {
                if (isbf) {
                    uint4 q = *reinterpret_cast<const uint4*>(xb + (size_t)n * 128 + ko * 8);
                    xv[r][0] = bf2f(q.x & 0xffffu); xv[r][1] = bf2f(q.x >> 16);
                    xv[r][2] = bf2f(q.y & 0xffffu); xv[r][3] = bf2f(q.y >> 16);
                    xv[r][4] = bf2f(q.z & 0xffffu); xv[r][5] = bf2f(q.z >> 16);
                    xv[r][6] = bf2f(q.w & 0xffffu); xv[r][7] = bf2f(q.w >> 16);
                } else {
                    const float4* p = reinterpret_cast<const float4*>(xf + (size_t)n * 128 + ko * 8);
                    float4 a = p[0], bb = p[1];
                    xv[r][0] = a.x; xv[r][1] = a.y; xv[r][2] = a.z; xv[r][3] = a.w;
                    xv[r][4] = bb.x; xv[r][5] = bb.y; xv[r][6] = bb.z; xv[r][7] = bb.w;
                }
            } else {
                #pragma unroll
                for (int u = 0; u < 8; ++u) xv[r][u] = 0.f;
            }
        }
        #pragma unroll
        for (int c = 0; c < 4; ++c) {
            const float* wr = &sWt[(hq * 4 + c) * 132 + ko * 8];
            float4 w0 = *reinterpret_cast<const float4*>(wr);
            float4 w1v = *reinterpret_cast<const float4*>(wr + 4);
            #pragma unroll
            for (int r = 0; r < 4; ++r) {
                acc[r][c] += xv[r][0] * w0.x + xv[r][1] * w0.y + xv[r][2] * w0.z + xv[r][3] * w0.w
                           + xv[r][4] * w1v.x + xv[r][5] * w1v.y + xv[r][6] * w1v.z + xv[r][7] * w1v.w;
            }
        }
    }
    #pragma unroll
    for (int r = 0; r < 4; ++r) {
        int n = n0 + r;
        if (n < Nn) {
            float dv = dinv[n];
            float4 o = make_float4(acc[r][0] * dv, acc[r][1] * dv, acc[r][2] * dv, acc[r][3] * dv);
            *reinterpret_cast<float4*>(hs + (size_t)n * 16 + hq * 4) = o;
            *reinterpret_cast<float4*>(agg + (size_t)n * 16 + hq * 4) = o;  // self-loop init
        }
    }
}

// ---------------- kernel: split bucket agg — chunk counting-sort + register runs ----------------
#define SPLITS 4
#define ACH 2048
__global__ __launch_bounds__(256) void k_aggS(const unsigned int* __restrict__ bkt,
                                              const int* __restrict__ base,
                                              const float* __restrict__ hs,
                                              float* __restrict__ agg, int Nn) {
    __shared__ float sAgg[4096];          // 256 nodes x 16 feat (16 KB)
    __shared__ unsigned int sSorted[ACH]; // 8 KB
    __shared__ int cnt[256], excl[256], cura[256];
    __shared__ int sc[2][256];
    __shared__ int tot_s;
    int tid = threadIdx.x;
    int b = blockIdx.x >> 2, sp = blockIdx.x & 3;
    for (int i = tid; i < 4096; i += 256) sAgg[i] = 0.f;
    int st = base[b], en = base[b + 1];
    int len = en - st;
    int s0 = st + (int)(((long long)len * sp) >> 2);
    int s1 = st + (int)(((long long)len * (sp + 1)) >> 2);
    int g = tid >> 4, j = tid & 15;
    for (int c0 = s0; c0 < s1; c0 += ACH) {
        int C = min(ACH, s1 - c0);
        cnt[tid] = 0;
        __syncthreads();
        // histogram by node-in-bucket (int LDS atomics)
        for (int r = tid; r < C; r += 256) {
            unsigned u = bkt[c0 + r];
            atomicAdd(&cnt[(u >> 17) & 255u], 1);
        }
        __syncthreads();
        // 256-wide scan
        int v = cnt[tid];
        sc[0][tid] = v;
        __syncthreads();
        int pi = 0;
        for (int off = 1; off < 256; off <<= 1) {
            sc[pi ^ 1][tid] = sc[pi][tid] + ((tid >= off) ? sc[pi][tid - off] : 0);
            __syncthreads();
            pi ^= 1;
        }
        int ex = sc[pi][tid] - v;
        excl[tid] = ex;
        cura[tid] = ex;
        if (tid == 255) tot_s = sc[pi][255];
        __syncthreads();
        // scatter into sorted order (re-read bkt chunk — L2 hot)
        for (int r = tid; r < C; r += 256) {
            unsigned u = bkt[c0 + r];
            int q = atomicAdd(&cura[(u >> 17) & 255u], 1);
            sSorted[q] = u;
        }
        __syncthreads();
        // register-run accumulation: group g owns nodes [g*16, g*16+16)
        int segS = excl[g * 16];
        int segE = (g == 15) ? tot_s : excl[g * 16 + 16];
        float acc = 0.f; int curn = -1;
        for (int k = segS; k < segE; k += 4) {
            int m = segE - k;
            unsigned e0 = sSorted[k];
            unsigned e1 = (m > 1) ? sSorted[k + 1] : 0u;
            unsigned e2 = (m > 2) ? sSorted[k + 2] : 0u;
            unsigned e3 = (m > 3) ? sSorted[k + 3] : 0u;
            float v0 = hs[(size_t)(e0 & 0x1ffffu) * 16 + j];
            float v1 = (m > 1) ? hs[(size_t)(e1 & 0x1ffffu) * 16 + j] : 0.f;
            float v2 = (m > 2) ? hs[(size_t)(e2 & 0x1ffffu) * 16 + j] : 0.f;
            float v3 = (m > 3) ? hs[(size_t)(e3 & 0x1ffffu) * 16 + j] : 0.f;
            int n0_ = (int)((e0 >> 17) & 255u);
            if (n0_ != curn) { if (curn >= 0) sAgg[curn * 16 + j] += acc; acc = 0.f; curn = n0_; }
            acc += v0;
            if (m > 1) {
                int nn = (int)((e1 >> 17) & 255u);
                if (nn != curn) { sAgg[curn * 16 + j] += acc; acc = 0.f; curn = nn; }
                acc += v1;
            }
            if (m > 2) {
                int nn = (int)((e2 >> 17) & 255u);
                if (nn != curn) { sAgg[curn * 16 + j] += acc; acc = 0.f; curn = nn; }
                acc += v2;
            }
            if (m > 3) {
                int nn = (int)((e3 >> 17) & 255u);
                if (nn != curn) { sAgg[curn * 16 + j] += acc; acc = 0.f; curn = nn; }
                acc += v3;
            }
        }
        if (curn >= 0) sAgg[curn * 16 + j] += acc;
        __syncthreads();
    }
    // coalesced zero-skip combine into global agg
    int nbase = b << 8;
    for (int i = tid; i < 4096; i += 256) {
        int n = nbase + (i >> 4);
        float v = sAgg[i];
        bool nz = (n < Nn) && (v != 0.f);
        if (__any(nz)) {
            if (n < Nn) atomAddF(&agg[(size_t)n * 16 + (i & 15)], v);
        }
    }
}

// ---------------- kernel: *dinv + bias + relu -> @Wp+bp -> softmax -> out ----------------
__global__ __launch_bounds__(256) void k_final(const float* __restrict__ agg,
                                               const float* __restrict__ dinv,
                                               const void* __restrict__ b1raw,
                                               const void* __restrict__ wpraw,
                                               const void* __restrict__ bpraw,
                                               const int* __restrict__ flags,
                                               void* __restrict__ outraw, int Nn) {
    __shared__ float sWp[256];
    __shared__ float sA[256];
    const int isbf = flags[0];
    int tid = threadIdx.x;
    sWp[tid] = isbf ? bf2f(((const ushort*)wpraw)[tid]) : ((const float*)wpraw)[tid];
    int n0 = blockIdx.x * 16;
    int nl = tid >> 4, c = tid & 15;
    int n = n0 + nl;
    float b1v = isbf ? bf2f(((const ushort*)b1raw)[c]) : ((const float*)b1raw)[c];
    float bpv = isbf ? bf2f(((const ushort*)bpraw)[c]) : ((const float*)bpraw)[c];
    float av = (n < Nn) ? agg[(size_t)n * 16 + c] * dinv[n] : 0.f;
    sA[tid] = fmaxf(av + b1v, 0.f);
    __syncthreads();
    float acc = bpv;
    #pragma unroll
    for (int jj = 0; jj < 16; ++jj) acc += sA[nl * 16 + jj] * sWp[jj * 16 + c];
    float m = acc;
    #pragma unroll
    for (int off = 1; off < 16; off <<= 1) m = fmaxf(m, __shfl_xor(m, off, 16));
    float ev = __expf(acc - m);
    float s = ev;
    #pragma unroll
    for (int off = 1; off < 16; off <<= 1) s += __shfl_xor(s, off, 16);
    if (n < Nn) {
        float v = ev / s;
        if (isbf) ((ushort*)outraw)[(size_t)n * 16 + c] = f2bf(v);
        else      ((float*)outraw)[(size_t)n * 16 + c] = v;
    }
}

extern "C" void kernel_launch(void* const* d_in, const int* in_sizes, int n_in,
                              void* d_out, int out_size, void* d_ws, size_t ws_size,
                              hipStream_t stream) {
    const void* x  = d_in[0];
    const void* W1 = d_in[1];
    const void* b1 = d_in[2];
    const void* Wp = d_in[3];
    const void* bp = d_in[4];
    const int*  ei = (const int*)d_in[5];

    int Nn = in_sizes[0] / 128;
    int E  = in_sizes[5] / 2;
    int NB = (Nn + 255) >> 8;

    size_t Ns = (size_t)Nn;
    char* ws = (char*)d_ws;
    size_t off = 0;
    auto alloc = [&](size_t bytes) { void* p = ws + off; off += (bytes + 63) & ~(size_t)63; return p; };
    int*          flags  = (int*)alloc(64);
    float*        hs     = (float*)alloc(Ns * 16 * 4);
    float*        agg    = (float*)alloc(Ns * 16 * 4);
    float*        dinv   = (float*)alloc(Ns * 4);
    int*          hist   = (int*)alloc(512 * 4);
    int*          basep  = (int*)alloc(513 * 4);
    int*          cursor = (int*)alloc(512 * 4);
    unsigned int* bkt    = (unsigned int*)alloc((size_t)E * 4);

    hipMemsetAsync(hist, 0, 512 * 4, stream);
    k_detect<<<1, 256, 0, stream>>>((const unsigned int*)x, (const unsigned int*)ei, flags);
    k_hist<<<(E + 8191) / 8192, 256, 0, stream>>>(ei, flags, hist, E, Nn);
    k_scanB<<<1, 512, 0, stream>>>(hist, basep, cursor, NB);
    k_part<<<(E + PCHUNK - 1) / PCHUNK, 256, 0, stream>>>(ei, flags, cursor, bkt, E, Nn);
    k_dinv<<<NB, 256, 0, stream>>>(bkt, basep, dinv, Nn);
    k_gemm1<<<(Nn + 255) / 256, 256, 0, stream>>>(x, W1, flags, dinv, hs, agg, Nn);
    k_aggS<<<NB * SPLITS, 256, 0, stream>>>(bkt, basep, hs, agg, Nn);
    k_final<<<(Nn + 15) / 16, 256, 0, stream>>>(agg, dinv, b1, Wp, bp, flags, d_out, Nn);
}